// Round 9
// baseline (165.597 us; speedup 1.0000x reference)
//
#include <hip/hip_runtime.h>
#include <math.h>

#define N_NODES  32
#define N_HEADS  4
#define CDIM     256           // N_HEADS * HEAD_DIM == channels
#define HWPIX    9216          // 96*96
#define ROWF4    2304          // HWPIX/4 float4 per (n,c) row
#define E_BASE   512
#define E_TOT    544           // + 32 self loops
#define NEG_SLOPE 0.2f
#define XS       257           // LDS stride for x tile (conflict-free)
#define GRID     1024          // MUST equal co-resident capacity (4 blk/CU x 256)

// ---------------------------------------------------------------------------
// Single fused kernel. All 1024 blocks pool 8 rows (2/wave) -> x in d_ws,
// then release via device-scope counter. Blocks 0..31 overlap all
// x-independent GAT work (Wa compute, edge prefetch, W L2-warm) with the
// grid's pooling, spin on the counter, then run the short x-dependent chain.
// LDS 39,152 B -> 4 blocks/CU; VGPR capped 128 by bounds -> 1024 co-resident,
// so the spin cannot deadlock.
// ---------------------------------------------------------------------------
__global__ __launch_bounds__(256, 4) void fused_kernel(
    const float* __restrict__ roi,
    const int*   __restrict__ edge_index,
    const float* __restrict__ W,
    const float* __restrict__ a_src,
    const float* __restrict__ a_dst,
    const float* __restrict__ gat_bias,
    const float* __restrict__ cls_W,
    const float* __restrict__ cls_b,
    float*       __restrict__ x,
    unsigned*    __restrict__ counter,
    float*       __restrict__ out)
{
    __shared__ float    xs[N_NODES * XS];      // 32,896 B
    __shared__ float    wasy[N_HEADS * CDIM];  // was[c][hd] then y[hd][c]; 4 KB
    __shared__ float    alsM[256];             // als[128] | M[128]; later red[256]
    __shared__ float    sv[CDIM];              // silu(out_gat)
    __shared__ float    adn[N_HEADS];
    __shared__ unsigned msegu[N_HEADS];
    __shared__ float    dseg[N_HEADS];
    __shared__ float    wscr[16];              // cross-wave reduce scratch

    const int t = threadIdx.x;
    const int wave = t >> 6, lane = t & 63;

    // ===================== pool phase: 2 rows per wave =====================
#pragma unroll
    for (int r = 0; r < 2; ++r) {
        const int row = (blockIdx.x * 4 + wave) * 2 + r;       // 0..8191
        const float4* p = (const float4*)roi + (size_t)row * ROWF4 + lane;
        float4 A[12], B[12];
        float s = 0.f;
#pragma unroll
        for (int j = 0; j < 12; ++j) A[j] = p[j * 64];
#pragma unroll
        for (int j = 0; j < 12; ++j) B[j] = p[(12 + j) * 64];
#pragma unroll
        for (int j = 0; j < 12; ++j) s += (A[j].x + A[j].y) + (A[j].z + A[j].w);
#pragma unroll
        for (int j = 0; j < 12; ++j) A[j] = p[(24 + j) * 64];
#pragma unroll
        for (int j = 0; j < 12; ++j) s += (B[j].x + B[j].y) + (B[j].z + B[j].w);
#pragma unroll
        for (int j = 0; j < 12; ++j) s += (A[j].x + A[j].y) + (A[j].z + A[j].w);
#pragma unroll
        for (int off = 32; off; off >>= 1) s += __shfl_down(s, off);
        if (lane == 0) x[row] = s * (1.0f / (float)HWPIX);
    }
    __syncthreads();                           // all block's x writes issued+acked
    if (t == 0) {
        __threadfence();                       // agent-scope release (L2 writeback)
        __hip_atomic_fetch_add(counter, 1u, __ATOMIC_RELEASE,
                               __HIP_MEMORY_SCOPE_AGENT);
    }
    if (blockIdx.x >= N_NODES) return;         // producers done

    // ============== consumer pre-sync work (x-independent) =================
    const int n = blockIdx.x;                  // dst node this block owns

    float wadreg[N_HEADS];                     // W.a_dst, channel t, in regs
    {
        float accs[4] = {0.f, 0.f, 0.f, 0.f};
        float accd[4] = {0.f, 0.f, 0.f, 0.f};
        const float4* wr  = (const float4*)(W + t * CDIM);     // warms W in L2
        const float4* as4 = (const float4*)a_src;
        const float4* ad4 = (const float4*)a_dst;
#pragma unroll 16
        for (int q = 0; q < 64; ++q) {
            const float4 w = wr[q], av = as4[q], dv = ad4[q];
            const int hd = q >> 4;
            accs[hd] += w.x*av.x + w.y*av.y + w.z*av.z + w.w*av.w;
            accd[hd] += w.x*dv.x + w.y*dv.y + w.z*dv.z + w.w*dv.w;
        }
#pragma unroll
        for (int hd = 0; hd < 4; ++hd) {
            wasy[t * 4 + hd] = accs[hd];       // was[c=t][hd]
            wadreg[hd] = accd[hd];
        }
    }

    // edge prefetch into registers (e = t, t+256, t+512)
    int es[3], ed[3];
    es[0] = edge_index[t];        ed[0] = edge_index[E_BASE + t];
    es[1] = edge_index[t + 256];  ed[1] = edge_index[E_BASE + t + 256];
    es[2] = t;                    ed[2] = (t < E_TOT - E_BASE) ? t : -1;

    if (t < 128) alsM[128 + t] = 0.f;          // M = 0
    if (t < 4)   { msegu[t] = 0u; dseg[t] = 0.f; }

    // ===================== spin until pool complete ========================
    if (t == 0) {
        while (__hip_atomic_load(counter, __ATOMIC_RELAXED,
                                 __HIP_MEMORY_SCOPE_AGENT) < GRID)
            __builtin_amdgcn_s_sleep(2);
        __threadfence();                       // agent-scope acquire (inv caches)
    }
    __syncthreads();

    // ===================== stage x into LDS (stride 257) ===================
#pragma unroll
    for (int k = 0; k < 8; ++k) {
        const int i4 = t + k * 256;            // 0..2047
        const float4 v = ((const float4*)x)[i4];
        const int i = i4 * 4, s = i >> 8, c = i & 255;
        xs[s * XS + c + 0] = v.x;
        xs[s * XS + c + 1] = v.y;
        xs[s * XS + c + 2] = v.z;
        xs[s * XS + c + 3] = v.w;
    }
    __syncthreads();

    // ====== adn[hd] = x[n,:] . wad  (all-thread shuffle+LDS reduction) =====
    {
        const float xv = xs[n * XS + t];
        float p0 = xv * wadreg[0], p1 = xv * wadreg[1];
        float p2 = xv * wadreg[2], p3 = xv * wadreg[3];
#pragma unroll
        for (int off = 32; off; off >>= 1) {
            p0 += __shfl_down(p0, off); p1 += __shfl_down(p1, off);
            p2 += __shfl_down(p2, off); p3 += __shfl_down(p3, off);
        }
        if (lane == 0) {
            wscr[wave * 4 + 0] = p0; wscr[wave * 4 + 1] = p1;
            wscr[wave * 4 + 2] = p2; wscr[wave * 4 + 3] = p3;
        }
    }
    __syncthreads();
    if (t < 4) adn[t] = wscr[t] + wscr[4 + t] + wscr[8 + t] + wscr[12 + t];

    // alphas: als[s,hd] = xs[s,:] . was[:,hd]
    if (t < 128) {
        const int s = t >> 2, hd = t & 3;
        const float* xrow = &xs[s * XS];
        float acc = 0.f;
#pragma unroll 8
        for (int c = 0; c < CDIM; ++c) acc += xrow[c] * wasy[c * 4 + hd];
        alsM[t] = acc;
    }
    __syncthreads();

    // pass A: segment max (monotone uint atomicMax on LDS)
#pragma unroll
    for (int k = 0; k < 3; ++k) {
        if (ed[k] == n) {
#pragma unroll
            for (int hd = 0; hd < 4; ++hd) {
                float v = alsM[es[k] * 4 + hd] + adn[hd];
                v = (v >= 0.f) ? v : NEG_SLOPE * v;
                const int iv = __float_as_int(v);
                const unsigned key = (iv < 0) ? ~(unsigned)iv
                                              : ((unsigned)iv | 0x80000000u);
                atomicMax(&msegu[hd], key);
            }
        }
    }
    __syncthreads();

    float mx[4];
#pragma unroll
    for (int hd = 0; hd < 4; ++hd) {
        const unsigned key = msegu[hd];
        const int im = (key & 0x80000000u) ? (int)(key & 0x7fffffffu) : (int)~key;
        mx[hd] = __int_as_float(im);
    }

    // pass B: exp, denom, unnormalized attention row (dups sum correctly)
#pragma unroll
    for (int k = 0; k < 3; ++k) {
        if (ed[k] == n) {
#pragma unroll
            for (int hd = 0; hd < 4; ++hd) {
                float v = alsM[es[k] * 4 + hd] + adn[hd];
                v = (v >= 0.f) ? v : NEG_SLOPE * v;
                const float ex = expf(v - mx[hd]);
                atomicAdd(&dseg[hd], ex);
                atomicAdd(&alsM[128 + es[k] * 4 + hd], ex);
            }
        }
    }
    __syncthreads();
    if (t < 128) alsM[128 + t] /= dseg[t & 3];
    __syncthreads();

    // y[hd,c] = sum_s M[s,hd] * xs[s,c]  -> overlays was (dead after alphas)
    {
        const int hd = t >> 6;
        float a0 = 0.f, a1 = 0.f, a2 = 0.f, a3 = 0.f;
#pragma unroll
        for (int s = 0; s < N_NODES; ++s) {
            const float m = alsM[128 + s * 4 + hd];    // wave-uniform broadcast
            const float* xrow = &xs[s * XS + lane];
            a0 += m * xrow[0];   a1 += m * xrow[64];
            a2 += m * xrow[128]; a3 += m * xrow[192];
        }
        wasy[hd * CDIM + lane]       = a0;
        wasy[hd * CDIM + lane + 64]  = a1;
        wasy[hd * CDIM + lane + 128] = a2;
        wasy[hd * CDIM + lane + 192] = a3;
    }
    __syncthreads();

    // out_gat[t] = y[hd,:] . W[:,t] + bias; SiLU  (W is L2-hot from Wa phase)
    {
        const int hd = t >> 6;
        const float* yrow = &wasy[hd * CDIM];
        float acc = 0.f;
#pragma unroll 16
        for (int c = 0; c < CDIM; ++c) acc += yrow[c] * W[c * CDIM + t];
        const float v = acc + gat_bias[t];
        sv[t] = v / (1.0f + expf(-v));
    }
    __syncthreads();

    // classifier: 8 groups x 32 cols, partials into red (overlays als|M)
    {
        const int j = t & 31, g = t >> 5;
        float a = 0.f;
#pragma unroll
        for (int c0 = 0; c0 < 32; ++c0) {
            const int c = g * 32 + c0;
            a += sv[c] * cls_W[c * 32 + j];
        }
        alsM[g * 32 + j] = a;
    }
    __syncthreads();
    if (t < 32) {
        float s2 = cls_b[t];
#pragma unroll
        for (int g2 = 0; g2 < 8; ++g2) s2 += alsM[g2 * 32 + t];
        out[n * 32 + t] = s2;
    }
}

// ---------------------------------------------------------------------------
extern "C" void kernel_launch(void* const* d_in, const int* in_sizes, int n_in,
                              void* d_out, int out_size, void* d_ws, size_t ws_size,
                              hipStream_t stream) {
    const float* roi   = (const float*)d_in[0];
    const int*   eidx  = (const int*)d_in[1];
    const float* W     = (const float*)d_in[2];
    const float* a_src = (const float*)d_in[3];
    const float* a_dst = (const float*)d_in[4];
    const float* gbias = (const float*)d_in[5];
    const float* clsW  = (const float*)d_in[6];
    const float* clsb  = (const float*)d_in[7];
    float* out = (float*)d_out;

    unsigned* counter = (unsigned*)d_ws;               // [0..64) bytes
    float*    x       = (float*)((char*)d_ws + 256);   // [8192] floats

    hipMemsetAsync(d_ws, 0, 64, stream);               // zero counter per replay
    fused_kernel<<<GRID, 256, 0, stream>>>(roi, eidx, W, a_src, a_dst,
                                           gbias, clsW, clsb, x, counter, out);
}